// Round 2
// baseline (576.767 us; speedup 1.0000x reference)
//
#include <hip/hip_runtime.h>

#define EPS 1e-5f
#define APITCH 264   // bf16 tile row pitch (shorts): 256 + 8 pad

typedef __attribute__((ext_vector_type(8))) short bf16x8;
typedef __attribute__((ext_vector_type(4))) float f32x4;

__device__ __forceinline__ unsigned short f2b(float f) {
  unsigned int u = __builtin_bit_cast(unsigned int, f);
  u += 0x7fffu + ((u >> 16) & 1u);   // round-to-nearest-even
  return (unsigned short)(u >> 16);
}
__device__ __forceinline__ float bhalf(unsigned int pk, int hi) {
  unsigned int u = hi ? (pk & 0xffff0000u) : (pk << 16);
  return __builtin_bit_cast(float, u);
}

// 32 rows x 256 f32 (global, coalesced float4) -> bf16 LDS tile
__device__ __forceinline__ void load_rows_bf16(const float* __restrict__ src,
                                               short* aT, int t) {
#pragma unroll
  for (int j = 0; j < 8; j++) {
    const int idx4 = j * 256 + t;
    const int row = idx4 >> 6;
    const int c4 = (idx4 & 63) << 2;
    const float4 v = *(const float4*)&src[row * 256 + c4];
    short* p = &aT[row * APITCH + c4];
    p[0] = (short)f2b(v.x); p[1] = (short)f2b(v.y);
    p[2] = (short)f2b(v.z); p[3] = (short)f2b(v.w);
  }
}

__device__ __forceinline__ void loadA(const short* src, bf16x8 (&a0)[8],
                                      bf16x8 (&a1)[8], int lr, int lh) {
#pragma unroll
  for (int kk = 0; kk < 8; kk++) {
    a0[kk] = *(const bf16x8*)&src[lr * APITCH + kk * 32 + lh * 8];
    a1[kk] = *(const bf16x8*)&src[(16 + lr) * APITCH + kk * 32 + lh * 8];
  }
}

__device__ __forceinline__ void zeroAcc(f32x4 (&acc)[4][2]) {
#pragma unroll
  for (int q = 0; q < 4; q++)
#pragma unroll
    for (int rh = 0; rh < 2; rh++)
      acc[q][rh] = (f32x4){0.f, 0.f, 0.f, 0.f};
}

// 32 rows x 64 cols (4 col-tiles) = A(32x256) @ W[rowBase..rowBase+63]^T
__device__ __forceinline__ void gemmPass(const bf16x8 (&a0)[8], const bf16x8 (&a1)[8],
                                         const unsigned short* __restrict__ Wb,
                                         int rowBase, f32x4 (&acc)[4][2],
                                         int lr, int lh) {
#pragma unroll
  for (int q = 0; q < 4; q++) {
    bf16x8 b[8];
#pragma unroll
    for (int kk = 0; kk < 8; kk++)
      b[kk] = *(const bf16x8*)&Wb[(size_t)(rowBase + q * 16 + lr) * 256 + kk * 32 + lh * 8];
#pragma unroll
    for (int kk = 0; kk < 8; kk++) {
      acc[q][0] = __builtin_amdgcn_mfma_f32_16x16x32_bf16(a0[kk], b[kk], acc[q][0], 0, 0, 0);
      acc[q][1] = __builtin_amdgcn_mfma_f32_16x16x32_bf16(a1[kk], b[kk], acc[q][1], 0, 0, 0);
    }
  }
}

// per-row partial (sum, sumsq) over this wave's 64 cols -> LDS partials
__device__ __forceinline__ void statsWrite(const f32x4 (&acc)[4][2], const float (&b4)[4],
                                           float* sP, float* qP, int wv, int lr, int lh) {
#pragma unroll
  for (int rh = 0; rh < 2; rh++)
#pragma unroll
    for (int i = 0; i < 4; i++) {
      float s = 0.f, qq = 0.f;
#pragma unroll
      for (int q = 0; q < 4; q++) {
        float v = acc[q][rh][i] + b4[q];
        s += v; qq += v * v;
      }
#pragma unroll
      for (int m = 1; m < 16; m <<= 1) { s += __shfl_xor(s, m); qq += __shfl_xor(qq, m); }
      if (lr == 0) {
        int row = rh * 16 + lh * 4 + i;
        sP[wv * 32 + row] = s; qP[wv * 32 + row] = qq;
      }
    }
}
__device__ __forceinline__ void statsRead(const float* sP, const float* qP,
                                          float (&mu)[2][4], float (&rs)[2][4], int lh) {
#pragma unroll
  for (int rh = 0; rh < 2; rh++)
#pragma unroll
    for (int i = 0; i < 4; i++) {
      int row = rh * 16 + lh * 4 + i;
      float S = sP[row] + sP[32 + row] + sP[64 + row] + sP[96 + row];
      float Q = qP[row] + qP[32 + row] + qP[64 + row] + qP[96 + row];
      float m = S * (1.f / 256.f);
      mu[rh][i] = m;
      rs[rh][i] = rsqrtf(Q * (1.f / 256.f) - m * m + EPS);
    }
}

__device__ __forceinline__ void red8(float& s, float& q) {
#pragma unroll
  for (int m = 1; m < 8; m <<= 1) { s += __shfl_xor(s, m); q += __shfl_xor(q, m); }
}

// ---------------- main fused kernel: register-resident pipeline ----------------
__global__ __launch_bounds__(256, 2) void k_main(
    const float* __restrict__ inf,
    const unsigned short* __restrict__ inpW, const float* __restrict__ inpb,
    const unsigned short* __restrict__ igW, const float* __restrict__ igb,
    const unsigned short* __restrict__ ugW, const float* __restrict__ ugb,
    const unsigned short* __restrict__ fcW, const float* __restrict__ fcb,
    const float* __restrict__ nig, const float* __restrict__ nib,   // norm_in (U gate)
    const float* __restrict__ iig, const float* __restrict__ iib,   // inorm_in (P gate)
    const float* __restrict__ iog, const float* __restrict__ iob,   // inorm_out
    const float* __restrict__ fng, const float* __restrict__ fnb,   // fc_norm
    const float* __restrict__ param_in, const float* __restrict__ param_out_ln,
    float* __restrict__ out) {
  __shared__ short aT[32 * APITCH];   // input tile, later features tile
  __shared__ short gT[32 * APITCH];   // gate_feats tile
  __shared__ float sA[128], qA[128], sB[128], qB[128];

  const int t = threadIdx.x;
  const int wv = t >> 6, lane = t & 63, lr = lane & 15, lh = lane >> 4;
  const int r0 = blockIdx.x * 32;
  const int cb = wv * 64;             // this wave's column base

  load_rows_bf16(&inf[(size_t)r0 * 256], aT, t);

  int nrow[8];
#pragma unroll
  for (int rh = 0; rh < 2; rh++)
#pragma unroll
    for (int i = 0; i < 4; i++)
      nrow[rh * 4 + i] = (r0 + rh * 16 + lh * 4 + i) / 9;

  __syncthreads();                                      // S1

  bf16x8 a0[8], a1[8];
  loadA(aT, a0, a1, lr, lh);

  f32x4 acc[4][2];
  float b4[4];
  float mu[2][4], rs[2][4];

  // ---- GEMM1 in-half: input_in -> gate_feats (bf16) -> gT ----
  zeroAcc(acc);
  gemmPass(a0, a1, inpW, cb, acc, lr, lh);
#pragma unroll
  for (int q = 0; q < 4; q++) {
    const int col = cb + q * 16 + lr;
    const float bi = inpb[col];
#pragma unroll
    for (int rh = 0; rh < 2; rh++)
#pragma unroll
      for (int i = 0; i < 4; i++) {
        float g = (acc[q][rh][i] + bi) * param_in[(size_t)nrow[rh * 4 + i] * 256 + col];
        gT[(rh * 16 + lh * 4 + i) * APITCH + col] = (short)f2b(g);
      }
  }

  // ---- GEMM1 out-half: input_out, LN in-register ----
  zeroAcc(acc);
  gemmPass(a0, a1, inpW, 256 + cb, acc, lr, lh);
#pragma unroll
  for (int q = 0; q < 4; q++) b4[q] = inpb[256 + cb + q * 16 + lr];
  statsWrite(acc, b4, sA, qA, wv, lr, lh);
  __syncthreads();                                      // S2 (gT + sA/qA ready)
  statsRead(sA, qA, mu, rs, lh);
  unsigned int ioln[4][2][2];
#pragma unroll
  for (int q = 0; q < 4; q++) {
    const int col = cb + q * 16 + lr;
    const float ga = iog[col], be = iob[col];
#pragma unroll
    for (int rh = 0; rh < 2; rh++) {
      float v0 = (acc[q][rh][0] + b4[q] - mu[rh][0]) * rs[rh][0] * ga + be;
      float v1 = (acc[q][rh][1] + b4[q] - mu[rh][1]) * rs[rh][1] * ga + be;
      float v2 = (acc[q][rh][2] + b4[q] - mu[rh][2]) * rs[rh][2] * ga + be;
      float v3 = (acc[q][rh][3] + b4[q] - mu[rh][3]) * rs[rh][3] * ga + be;
      ioln[q][rh][0] = (unsigned)f2b(v0) | ((unsigned)f2b(v1) << 16);
      ioln[q][rh][1] = (unsigned)f2b(v2) | ((unsigned)f2b(v3) << 16);
    }
  }

  // ---- gate GEMMs: P (input_gate path), U (update_gate path) ----
  loadA(gT, a0, a1, lr, lh);

  zeroAcc(acc);
  gemmPass(a0, a1, igW, cb, acc, lr, lh);
#pragma unroll
  for (int q = 0; q < 4; q++) b4[q] = igb[cb + q * 16 + lr];
  statsWrite(acc, b4, sB, qB, wv, lr, lh);
  __syncthreads();                                      // S3
  statsRead(sB, qB, mu, rs, lh);
  unsigned int g1p[4][2][2];
#pragma unroll
  for (int q = 0; q < 4; q++) {
    const int col = cb + q * 16 + lr;
    const float ga = iig[col], be = iib[col];
#pragma unroll
    for (int rh = 0; rh < 2; rh++) {
      float v[4];
#pragma unroll
      for (int i = 0; i < 4; i++) {
        float p = (acc[q][rh][i] + b4[q] - mu[rh][i]) * rs[rh][i] * ga + be;
        v[i] = 1.f / (1.f + __expf(-p));
      }
      g1p[q][rh][0] = (unsigned)f2b(v[0]) | ((unsigned)f2b(v[1]) << 16);
      g1p[q][rh][1] = (unsigned)f2b(v[2]) | ((unsigned)f2b(v[3]) << 16);
    }
  }

  zeroAcc(acc);
  gemmPass(a0, a1, ugW, cb, acc, lr, lh);
#pragma unroll
  for (int q = 0; q < 4; q++) b4[q] = ugb[cb + q * 16 + lr];
  statsWrite(acc, b4, sA, qA, wv, lr, lh);
  __syncthreads();                                      // S4
  statsRead(sA, qA, mu, rs, lh);
  // features = g2 * param_out_ln + g1 * ioLN -> aT (bf16)
#pragma unroll
  for (int q = 0; q < 4; q++) {
    const int col = cb + q * 16 + lr;
    const float ga = nig[col], be = nib[col];
#pragma unroll
    for (int rh = 0; rh < 2; rh++)
#pragma unroll
      for (int i = 0; i < 4; i++) {
        float u = (acc[q][rh][i] + b4[q] - mu[rh][i]) * rs[rh][i] * ga + be;
        float g2 = 1.f / (1.f + __expf(-u));
        float g1v = bhalf(g1p[q][rh][i >> 1], i & 1);
        float iov = bhalf(ioln[q][rh][i >> 1], i & 1);
        float po = param_out_ln[(size_t)nrow[rh * 4 + i] * 256 + col];
        aT[(rh * 16 + lh * 4 + i) * APITCH + col] = (short)f2b(g2 * po + g1v * iov);
      }
  }
  __syncthreads();                                      // S5

  // ---- GEMM4: fc + LN + relu -> out ----
  loadA(aT, a0, a1, lr, lh);
  zeroAcc(acc);
  gemmPass(a0, a1, fcW, cb, acc, lr, lh);
#pragma unroll
  for (int q = 0; q < 4; q++) b4[q] = fcb[cb + q * 16 + lr];
  statsWrite(acc, b4, sB, qB, wv, lr, lh);
  __syncthreads();                                      // S6
  statsRead(sB, qB, mu, rs, lh);
#pragma unroll
  for (int q = 0; q < 4; q++) {
    const int col = cb + q * 16 + lr;
    const float ga = fng[col], be = fnb[col];
#pragma unroll
    for (int rh = 0; rh < 2; rh++)
#pragma unroll
      for (int i = 0; i < 4; i++) {
        float v = (acc[q][rh][i] + b4[q] - mu[rh][i]) * rs[rh][i] * ga + be;
        out[(size_t)(r0 + rh * 16 + lh * 4 + i) * 256 + col] = fmaxf(v, 0.f);
      }
  }
}

// ---------------- kernel 1: params = uf @ dyn_W^T + dyn_b (unchanged) ----------------
#define FPITCH 516

__device__ __forceinline__ void gemm32(const short* aT,
                                       const unsigned short* __restrict__ Wb,
                                       const float* __restrict__ bias,
                                       float* fBuf, int fcolBase, int nct,
                                       int wv, int lane) {
  const int lr = lane & 15, lh = lane >> 4;
  for (int cp = 0; cp < nct; cp += 2) {
    const int ct0 = wv * nct + cp, ct1 = ct0 + 1;
    bf16x8 b0[8], b1[8];
#pragma unroll
    for (int kk = 0; kk < 8; kk++) {
      b0[kk] = *(const bf16x8*)&Wb[(ct0 * 16 + lr) * 256 + kk * 32 + lh * 8];
      b1[kk] = *(const bf16x8*)&Wb[(ct1 * 16 + lr) * 256 + kk * 32 + lh * 8];
    }
    const float bias0 = bias[ct0 * 16 + lr], bias1 = bias[ct1 * 16 + lr];
    f32x4 a00 = {0.f, 0.f, 0.f, 0.f}, a01 = a00, a10 = a00, a11 = a00;
#pragma unroll
    for (int kk = 0; kk < 8; kk++) {
      bf16x8 x0 = *(const bf16x8*)&aT[lr * APITCH + kk * 32 + lh * 8];
      bf16x8 x1 = *(const bf16x8*)&aT[(16 + lr) * APITCH + kk * 32 + lh * 8];
      a00 = __builtin_amdgcn_mfma_f32_16x16x32_bf16(x0, b0[kk], a00, 0, 0, 0);
      a10 = __builtin_amdgcn_mfma_f32_16x16x32_bf16(x1, b0[kk], a10, 0, 0, 0);
      a01 = __builtin_amdgcn_mfma_f32_16x16x32_bf16(x0, b1[kk], a01, 0, 0, 0);
      a11 = __builtin_amdgcn_mfma_f32_16x16x32_bf16(x1, b1[kk], a11, 0, 0, 0);
    }
#pragma unroll
    for (int i = 0; i < 4; i++) {
      const int rw = lh * 4 + i;
      fBuf[rw * FPITCH + fcolBase + ct0 * 16 + lr] = a00[i] + bias0;
      fBuf[rw * FPITCH + fcolBase + ct1 * 16 + lr] = a01[i] + bias1;
      fBuf[(16 + rw) * FPITCH + fcolBase + ct0 * 16 + lr] = a10[i] + bias0;
      fBuf[(16 + rw) * FPITCH + fcolBase + ct1 * 16 + lr] = a11[i] + bias1;
    }
  }
}

__global__ __launch_bounds__(256) void k_params(
    const float* __restrict__ uf, const unsigned short* __restrict__ dynW,
    const float* __restrict__ dynb, const float* __restrict__ nog,
    const float* __restrict__ nob, float* __restrict__ param_in,
    float* __restrict__ param_out_ln) {
  __shared__ short aT[32 * APITCH];
  __shared__ float fBuf[32 * FPITCH];
  const int t = threadIdx.x;
  const int r0 = blockIdx.x * 32;
  load_rows_bf16(&uf[(size_t)r0 * 256], aT, t);
  __syncthreads();
  gemm32(aT, dynW, dynb, fBuf, 0, 8, t >> 6, t & 63);
  __syncthreads();
  const int row = t >> 3, j = t & 7;
  float s = 0.f, q = 0.f;
#pragma unroll
  for (int i = 0; i < 32; i++) {
    float x = fBuf[row * FPITCH + 256 + j + 8 * i];
    s += x; q += x * x;
  }
  red8(s, q);
  const float mu = s * (1.f / 256.f);
  const float rsv = rsqrtf(q * (1.f / 256.f) - mu * mu + EPS);
  for (int i = 0; i < 32; i++) {
    const int c = j + 8 * i;
    float x = fBuf[row * FPITCH + 256 + c];
    param_out_ln[(size_t)(r0 + row) * 256 + c] = (x - mu) * rsv * nog[c] + nob[c];
  }
#pragma unroll
  for (int jj = 0; jj < 8; jj++) {
    const int idx4 = jj * 256 + t;
    const int rw = idx4 >> 6;
    const int c4 = (idx4 & 63) << 2;
    float4 v;
    v.x = fBuf[rw * FPITCH + c4 + 0];
    v.y = fBuf[rw * FPITCH + c4 + 1];
    v.z = fBuf[rw * FPITCH + c4 + 2];
    v.w = fBuf[rw * FPITCH + c4 + 3];
    *(float4*)&param_in[(size_t)(r0 + rw) * 256 + c4] = v;
  }
}

__global__ void k_cvt(const float* __restrict__ src,
                      unsigned short* __restrict__ dst, int n) {
  int i = blockIdx.x * blockDim.x + threadIdx.x;
  if (i < n) dst[i] = f2b(src[i]);
}

extern "C" void kernel_launch(void* const* d_in, const int* in_sizes, int n_in,
                              void* d_out, int out_size, void* d_ws, size_t ws_size,
                              hipStream_t stream) {
  const float* uf   = (const float*)d_in[0];
  const float* inf  = (const float*)d_in[1];
  const float* dynW = (const float*)d_in[2];
  const float* dynb = (const float*)d_in[3];
  const float* inpW = (const float*)d_in[4];
  const float* inpb = (const float*)d_in[5];
  const float* igW  = (const float*)d_in[6];
  const float* igb  = (const float*)d_in[7];
  const float* ugW  = (const float*)d_in[8];
  const float* ugb  = (const float*)d_in[9];
  const float* fcW  = (const float*)d_in[10];
  const float* fcb  = (const float*)d_in[11];
  const float* nig  = (const float*)d_in[12];
  const float* nib  = (const float*)d_in[13];
  const float* nog  = (const float*)d_in[14];
  const float* nob  = (const float*)d_in[15];
  const float* iig  = (const float*)d_in[16];
  const float* iib  = (const float*)d_in[17];
  const float* iog  = (const float*)d_in[18];
  const float* iob  = (const float*)d_in[19];
  const float* fng  = (const float*)d_in[20];
  const float* fnb  = (const float*)d_in[21];
  float* out = (float*)d_out;

  char* ws = (char*)d_ws;
  unsigned short* dynWb = (unsigned short*)(ws + 0);        // 262144 B
  unsigned short* inpWb = (unsigned short*)(ws + 262144);   // 262144 B
  unsigned short* igWb  = (unsigned short*)(ws + 524288);   // 131072 B
  unsigned short* ugWb  = (unsigned short*)(ws + 655360);   // 131072 B
  unsigned short* fcWb  = (unsigned short*)(ws + 786432);   // 131072 B
  float* param_in     = (float*)(ws + (1 << 20));                 // 16 MB
  float* param_out_ln = (float*)(ws + (1 << 20) + (16 << 20));    // 16 MB

  k_cvt<<<dim3(512), dim3(256), 0, stream>>>(dynW, dynWb, 131072);
  k_cvt<<<dim3(512), dim3(256), 0, stream>>>(inpW, inpWb, 131072);
  k_cvt<<<dim3(256), dim3(256), 0, stream>>>(igW, igWb, 65536);
  k_cvt<<<dim3(256), dim3(256), 0, stream>>>(ugW, ugWb, 65536);
  k_cvt<<<dim3(256), dim3(256), 0, stream>>>(fcW, fcWb, 65536);

  k_params<<<dim3(512), dim3(256), 0, stream>>>(uf, dynWb, dynb, nog, nob,
                                                param_in, param_out_ln);

  k_main<<<dim3(4608), dim3(256), 0, stream>>>(
      inf, inpWb, inpb, igWb, igb, ugWb, ugb, fcWb, fcb,
      nig, nib, iig, iib, iog, iob, fng, fnb,
      param_in, param_out_ln, out);
}

// Round 3
// 517.263 us; speedup vs baseline: 1.1150x; 1.1150x over previous
//
#include <hip/hip_runtime.h>

#define EPS 1e-5f
#define APITCH 264   // bf16 tile row pitch (shorts)
#define OPITCH 260   // f32 out-stage row pitch (floats)

typedef __attribute__((ext_vector_type(8))) short bf16x8;
typedef __attribute__((ext_vector_type(4))) float f32x4;

__device__ __forceinline__ unsigned short f2b(float f) {
  unsigned u = __builtin_bit_cast(unsigned, f);
  u += 0x7fffu + ((u >> 16) & 1u);   // RTNE
  return (unsigned short)(u >> 16);
}
__device__ __forceinline__ float bhalf(unsigned pk, int hi) {
  unsigned u = hi ? (pk & 0xffff0000u) : (pk << 16);
  return __builtin_bit_cast(float, u);
}

// Repack W (nrows x 256 f32) into MFMA-fragment-linear bf16:
// dst[(((ct*8+kk)*64+lane)*8)+j] = W[ct*16+(lane&15)][kk*32+(lane>>4)*8+j]
// so a wave's b-frag load (16B/lane) is a contiguous 1 KB stream.
__global__ void k_cvt_frag(const float* __restrict__ src,
                           unsigned short* __restrict__ dst, int n) {
  int i = blockIdx.x * blockDim.x + threadIdx.x;
  if (i >= n) return;
  int j = i & 7, lane = (i >> 3) & 63, kk = (i >> 9) & 7, ct = i >> 12;
  int row = ct * 16 + (lane & 15);
  int col = kk * 32 + (lane >> 4) * 8 + j;
  dst[i] = f2b(src[row * 256 + col]);
}

// ---------------- main fused kernel ----------------
// 512 threads = 8 waves; wave w: row-half rw=w>>2 (16 rows), col-quarter cv=w&3 (64 cols).
__global__ __launch_bounds__(512, 4) void k_main(
    const float* __restrict__ inf,
    const unsigned short* __restrict__ inpWf, const float* __restrict__ inpb,
    const unsigned short* __restrict__ igWf, const float* __restrict__ igb,
    const unsigned short* __restrict__ ugWf, const float* __restrict__ ugb,
    const unsigned short* __restrict__ fcWf, const float* __restrict__ fcb,
    const float* __restrict__ nig, const float* __restrict__ nib,
    const float* __restrict__ iig, const float* __restrict__ iib,
    const float* __restrict__ iog, const float* __restrict__ iob,
    const float* __restrict__ fng, const float* __restrict__ fnb,
    const float* __restrict__ param_in, const float* __restrict__ param_out_ln,
    float* __restrict__ out) {
  __shared__ __align__(16) char tileMem[33792];
  short* aTs = (short*)tileMem;                 // 32*264*2 = 16896 B
  short* gTs = (short*)(tileMem + 16896);       // 16896 B
  float* oS  = (float*)tileMem;                 // 32*260*4 = 33280 B overlay
  __shared__ float sP[2][128], qP[2][128];

  const int t = threadIdx.x;
  const int w = t >> 6, lane = t & 63, lr = lane & 15, lh = lane >> 4;
  const int rw = w >> 2, cv = w & 3, cb = cv * 64;
  const int r0 = blockIdx.x * 32;

  // stage 32x256 f32 -> bf16 LDS tile (coalesced float4)
#pragma unroll
  for (int j = 0; j < 4; j++) {
    const int idx4 = j * 512 + t;
    const int row = idx4 >> 6;
    const int c4 = (idx4 & 63) << 2;
    const float4 v = *(const float4*)&inf[(size_t)(r0 + row) * 256 + c4];
    short* p = &aTs[row * APITCH + c4];
    p[0] = (short)f2b(v.x); p[1] = (short)f2b(v.y);
    p[2] = (short)f2b(v.z); p[3] = (short)f2b(v.w);
  }

  int nrow[4];
#pragma unroll
  for (int i = 0; i < 4; i++) nrow[i] = (int)((unsigned)(r0 + rw * 16 + lh * 4 + i) / 9u);

  __syncthreads();

  bf16x8 a[8];
  f32x4 acc[4];
  unsigned gio[4][2];

#pragma unroll 1
  for (int ph = 0; ph < 5; ++ph) {
    const unsigned short* W;
    const float* bias;
    switch (ph) {
      case 0:  W = inpWf;             bias = inpb + cb;       break;
      case 1:  W = inpWf + 16 * 4096; bias = inpb + 256 + cb; break;
      case 2:  W = igWf;              bias = igb + cb;        break;
      case 3:  W = ugWf;              bias = ugb + cb;        break;
      default: W = fcWf;              bias = fcb + cb;        break;
    }
    if (ph == 0 || ph == 2 || ph == 4) {
      const short* src = (ph == 2) ? gTs : aTs;
#pragma unroll
      for (int kk = 0; kk < 8; kk++)
        a[kk] = *(const bf16x8*)&src[(rw * 16 + lr) * APITCH + kk * 32 + lh * 8];
    }
#pragma unroll
    for (int q = 0; q < 4; q++) acc[q] = (f32x4){0.f, 0.f, 0.f, 0.f};
#pragma unroll
    for (int q = 0; q < 4; q++) {
      const unsigned short* Wp = W + (cv * 4 + q) * 4096 + lane * 8;
      bf16x8 b[8];
#pragma unroll
      for (int kk = 0; kk < 8; kk++) b[kk] = *(const bf16x8*)&Wp[kk * 512];
#pragma unroll
      for (int kk = 0; kk < 8; kk++)
        acc[q] = __builtin_amdgcn_mfma_f32_16x16x32_bf16(a[kk], b[kk], acc[q], 0, 0, 0);
    }
    float b4[4];
#pragma unroll
    for (int q = 0; q < 4; q++) b4[q] = bias[q * 16 + lr];

    float mu[4], rs[4];
    if (ph) {
      const int par = ph & 1;
#pragma unroll
      for (int i = 0; i < 4; i++) {
        float s = 0.f, qq = 0.f;
#pragma unroll
        for (int q = 0; q < 4; q++) { float v = acc[q][i] + b4[q]; s += v; qq += v * v; }
#pragma unroll
        for (int m = 1; m < 16; m <<= 1) { s += __shfl_xor(s, m); qq += __shfl_xor(qq, m); }
        if (lr == 0) {
          const int r = rw * 16 + lh * 4 + i;
          sP[par][cv * 32 + r] = s; qP[par][cv * 32 + r] = qq;
        }
      }
      __syncthreads();
#pragma unroll
      for (int i = 0; i < 4; i++) {
        const int r = rw * 16 + lh * 4 + i;
        float S = sP[par][r] + sP[par][32 + r] + sP[par][64 + r] + sP[par][96 + r];
        float Q = qP[par][r] + qP[par][32 + r] + qP[par][64 + r] + qP[par][96 + r];
        float m = S * (1.f / 256.f);
        mu[i] = m;
        rs[i] = rsqrtf(Q * (1.f / 256.f) - m * m + EPS);
      }
    }

    switch (ph) {
      case 0:  // gate_feats = input_in * param_in -> gTs
#pragma unroll
        for (int q = 0; q < 4; q++) {
          const int col = cb + q * 16 + lr;
#pragma unroll
          for (int i = 0; i < 4; i++) {
            float g = (acc[q][i] + b4[q]) * param_in[(size_t)nrow[i] * 256 + col];
            gTs[(rw * 16 + lh * 4 + i) * APITCH + col] = (short)f2b(g);
          }
        }
        break;
      case 1:  // ioLN kept packed in regs
#pragma unroll
        for (int q = 0; q < 4; q++) {
          const int col = cb + q * 16 + lr;
          const float ga = iog[col], be = iob[col];
          float v[4];
#pragma unroll
          for (int i = 0; i < 4; i++)
            v[i] = (acc[q][i] + b4[q] - mu[i]) * rs[i] * ga + be;
          gio[q][0] = (unsigned)f2b(v[0]) | ((unsigned)f2b(v[1]) << 16);
          gio[q][1] = (unsigned)f2b(v[2]) | ((unsigned)f2b(v[3]) << 16);
        }
        break;
      case 2:  // g1 = sigmoid(LN); gio <- g1 * ioLN
#pragma unroll
        for (int q = 0; q < 4; q++) {
          const int col = cb + q * 16 + lr;
          const float ga = iig[col], be = iib[col];
          float v[4];
#pragma unroll
          for (int i = 0; i < 4; i++) {
            float p = (acc[q][i] + b4[q] - mu[i]) * rs[i] * ga + be;
            float g1 = 1.f / (1.f + __expf(-p));
            v[i] = g1 * bhalf(gio[q][i >> 1], i & 1);
          }
          gio[q][0] = (unsigned)f2b(v[0]) | ((unsigned)f2b(v[1]) << 16);
          gio[q][1] = (unsigned)f2b(v[2]) | ((unsigned)f2b(v[3]) << 16);
        }
        break;
      case 3:  // features = sigmoid(LN)*param_out_ln + gio -> aTs
#pragma unroll
        for (int q = 0; q < 4; q++) {
          const int col = cb + q * 16 + lr;
          const float ga = nig[col], be = nib[col];
#pragma unroll
          for (int i = 0; i < 4; i++) {
            float u = (acc[q][i] + b4[q] - mu[i]) * rs[i] * ga + be;
            float g2 = 1.f / (1.f + __expf(-u));
            float po = param_out_ln[(size_t)nrow[i] * 256 + col];
            float ft = g2 * po + bhalf(gio[q][i >> 1], i & 1);
            aTs[(rw * 16 + lh * 4 + i) * APITCH + col] = (short)f2b(ft);
          }
        }
        __syncthreads();   // aTs(features) ready for ph4 loadA
        break;
      default: // fc LN + relu -> f32 out-stage (overlays aTs/gTs; safe: post-barrier)
#pragma unroll
        for (int q = 0; q < 4; q++) {
          const int col = cb + q * 16 + lr;
          const float ga = fng[col], be = fnb[col];
#pragma unroll
          for (int i = 0; i < 4; i++) {
            float v = (acc[q][i] + b4[q] - mu[i]) * rs[i] * ga + be;
            oS[(rw * 16 + lh * 4 + i) * OPITCH + col] = fmaxf(v, 0.f);
          }
        }
        break;
    }
  }
  __syncthreads();
#pragma unroll
  for (int j = 0; j < 4; j++) {
    const int idx4 = j * 512 + t;
    const int row = idx4 >> 6;
    const int c4 = (idx4 & 63) << 2;
    float4 v;
    v.x = oS[row * OPITCH + c4 + 0];
    v.y = oS[row * OPITCH + c4 + 1];
    v.z = oS[row * OPITCH + c4 + 2];
    v.w = oS[row * OPITCH + c4 + 3];
    *(float4*)&out[(size_t)(r0 + row) * 256 + c4] = v;
  }
}

// ---------------- kernel 1: params = uf @ dyn_W^T + dyn_b ----------------
#define FPITCH 516

__device__ __forceinline__ void red8(float& s, float& q) {
#pragma unroll
  for (int m = 1; m < 8; m <<= 1) { s += __shfl_xor(s, m); q += __shfl_xor(q, m); }
}

__global__ __launch_bounds__(256) void k_params(
    const float* __restrict__ uf, const unsigned short* __restrict__ dynWf,
    const float* __restrict__ dynb, const float* __restrict__ nog,
    const float* __restrict__ nob, float* __restrict__ param_in,
    float* __restrict__ param_out_ln) {
  __shared__ short aT[32 * APITCH];
  __shared__ float fBuf[32 * FPITCH];
  const int t = threadIdx.x;
  const int wv = t >> 6, lane = t & 63, lr = lane & 15, lh = lane >> 4;
  const int r0 = blockIdx.x * 32;
#pragma unroll
  for (int j = 0; j < 8; j++) {
    const int idx4 = j * 256 + t;
    const int row = idx4 >> 6;
    const int c4 = (idx4 & 63) << 2;
    const float4 v = *(const float4*)&uf[(size_t)(r0 + row) * 256 + c4];
    short* p = &aT[row * APITCH + c4];
    p[0] = (short)f2b(v.x); p[1] = (short)f2b(v.y);
    p[2] = (short)f2b(v.z); p[3] = (short)f2b(v.w);
  }
  __syncthreads();
  bf16x8 a0[8], a1[8];
#pragma unroll
  for (int kk = 0; kk < 8; kk++) {
    a0[kk] = *(const bf16x8*)&aT[lr * APITCH + kk * 32 + lh * 8];
    a1[kk] = *(const bf16x8*)&aT[(16 + lr) * APITCH + kk * 32 + lh * 8];
  }
#pragma unroll 1
  for (int cp = 0; cp < 8; cp++) {
    const int ct = wv * 8 + cp;
    bf16x8 b[8];
#pragma unroll
    for (int kk = 0; kk < 8; kk++)
      b[kk] = *(const bf16x8*)&dynWf[((ct * 8 + kk) * 64 + lane) * 8];
    const float bi = dynb[ct * 16 + lr];
    f32x4 c0 = {0.f, 0.f, 0.f, 0.f}, c1 = c0;
#pragma unroll
    for (int kk = 0; kk < 8; kk++) {
      c0 = __builtin_amdgcn_mfma_f32_16x16x32_bf16(a0[kk], b[kk], c0, 0, 0, 0);
      c1 = __builtin_amdgcn_mfma_f32_16x16x32_bf16(a1[kk], b[kk], c1, 0, 0, 0);
    }
#pragma unroll
    for (int i = 0; i < 4; i++) {
      fBuf[(lh * 4 + i) * FPITCH + ct * 16 + lr] = c0[i] + bi;
      fBuf[(16 + lh * 4 + i) * FPITCH + ct * 16 + lr] = c1[i] + bi;
    }
  }
  __syncthreads();
  const int row = t >> 3, j = t & 7;
  float s = 0.f, q = 0.f;
#pragma unroll
  for (int i = 0; i < 32; i++) {
    float x = fBuf[row * FPITCH + 256 + j + 8 * i];
    s += x; q += x * x;
  }
  red8(s, q);
  const float mu = s * (1.f / 256.f);
  const float rsv = rsqrtf(q * (1.f / 256.f) - mu * mu + EPS);
#pragma unroll 1
  for (int i = 0; i < 32; i++) {
    const int c = j + 8 * i;
    float x = fBuf[row * FPITCH + 256 + c];
    param_out_ln[(size_t)(r0 + row) * 256 + c] = (x - mu) * rsv * nog[c] + nob[c];
  }
#pragma unroll
  for (int jj = 0; jj < 8; jj++) {
    const int idx4 = jj * 256 + t;
    const int rwq = idx4 >> 6;
    const int c4 = (idx4 & 63) << 2;
    float4 v;
    v.x = fBuf[rwq * FPITCH + c4 + 0];
    v.y = fBuf[rwq * FPITCH + c4 + 1];
    v.z = fBuf[rwq * FPITCH + c4 + 2];
    v.w = fBuf[rwq * FPITCH + c4 + 3];
    *(float4*)&param_in[(size_t)(r0 + rwq) * 256 + c4] = v;
  }
}

extern "C" void kernel_launch(void* const* d_in, const int* in_sizes, int n_in,
                              void* d_out, int out_size, void* d_ws, size_t ws_size,
                              hipStream_t stream) {
  const float* uf   = (const float*)d_in[0];
  const float* inf  = (const float*)d_in[1];
  const float* dynW = (const float*)d_in[2];
  const float* dynb = (const float*)d_in[3];
  const float* inpW = (const float*)d_in[4];
  const float* inpb = (const float*)d_in[5];
  const float* igW  = (const float*)d_in[6];
  const float* igb  = (const float*)d_in[7];
  const float* ugW  = (const float*)d_in[8];
  const float* ugb  = (const float*)d_in[9];
  const float* fcW  = (const float*)d_in[10];
  const float* fcb  = (const float*)d_in[11];
  const float* nig  = (const float*)d_in[12];
  const float* nib  = (const float*)d_in[13];
  const float* nog  = (const float*)d_in[14];
  const float* nob  = (const float*)d_in[15];
  const float* iig  = (const float*)d_in[16];
  const float* iib  = (const float*)d_in[17];
  const float* iog  = (const float*)d_in[18];
  const float* iob  = (const float*)d_in[19];
  const float* fng  = (const float*)d_in[20];
  const float* fnb  = (const float*)d_in[21];
  float* out = (float*)d_out;

  char* ws = (char*)d_ws;
  unsigned short* dynWf = (unsigned short*)(ws + 0);        // 262144 B
  unsigned short* inpWf = (unsigned short*)(ws + 262144);   // 262144 B
  unsigned short* igWf  = (unsigned short*)(ws + 524288);   // 131072 B
  unsigned short* ugWf  = (unsigned short*)(ws + 655360);   // 131072 B
  unsigned short* fcWf  = (unsigned short*)(ws + 786432);   // 131072 B
  float* param_in     = (float*)(ws + (1 << 20));
  float* param_out_ln = (float*)(ws + (1 << 20) + (16 << 20));

  k_cvt_frag<<<dim3(512), dim3(256), 0, stream>>>(dynW, dynWf, 131072);
  k_cvt_frag<<<dim3(512), dim3(256), 0, stream>>>(inpW, inpWf, 131072);
  k_cvt_frag<<<dim3(256), dim3(256), 0, stream>>>(igW, igWf, 65536);
  k_cvt_frag<<<dim3(256), dim3(256), 0, stream>>>(ugW, ugWf, 65536);
  k_cvt_frag<<<dim3(256), dim3(256), 0, stream>>>(fcW, fcWf, 65536);

  k_params<<<dim3(512), dim3(256), 0, stream>>>(uf, dynWf, dynb, nog, nob,
                                                param_in, param_out_ln);

  k_main<<<dim3(4608), dim3(512), 0, stream>>>(
      inf, inpWf, inpb, igWf, igb, ugWf, ugb, fcWf, fcb,
      nig, nib, iig, iib, iog, iob, fng, fnb,
      param_in, param_out_ln, out);
}

// Round 4
// 501.558 us; speedup vs baseline: 1.1500x; 1.0313x over previous
//
#include <hip/hip_runtime.h>

#define EPS 1e-5f
#define APITCH 264   // bf16 tile row pitch (shorts)

typedef __attribute__((ext_vector_type(8))) short bf16x8;
typedef __attribute__((ext_vector_type(4))) float f32x4;

__device__ __forceinline__ unsigned short f2b(float f) {
  unsigned u = __builtin_bit_cast(unsigned, f);
  u += 0x7fffu + ((u >> 16) & 1u);   // RTNE
  return (unsigned short)(u >> 16);
}
__device__ __forceinline__ float bhalf(unsigned pk, int hi) {
  unsigned u = hi ? (pk & 0xffff0000u) : (pk << 16);
  return __builtin_bit_cast(float, u);
}

// Repack W (nrows x 256 f32) into MFMA-fragment-linear bf16:
// dst[(((ct*8+kk)*64+lane)*8)+j] = W[ct*16+(lane&15)][kk*32+(lane>>4)*8+j]
__global__ void k_cvt_frag(const float* __restrict__ src,
                           unsigned short* __restrict__ dst, int n) {
  int i = blockIdx.x * blockDim.x + threadIdx.x;
  if (i >= n) return;
  int j = i & 7, lane = (i >> 3) & 63, kk = (i >> 9) & 7, ct = i >> 12;
  int row = ct * 16 + (lane & 15);
  int col = kk * 32 + (lane >> 4) * 8 + j;
  dst[i] = f2b(src[row * 256 + col]);
}

// load both 16-row halves of a 32x256 bf16 tile into a-frags (16 ds_read_b128)
__device__ __forceinline__ void loadA2(const short* src, bf16x8 (&a)[2][8],
                                       int lr, int lh) {
#pragma unroll
  for (int kk = 0; kk < 8; kk++) {
    a[0][kk] = *(const bf16x8*)&src[lr * APITCH + kk * 32 + lh * 8];
    a[1][kk] = *(const bf16x8*)&src[(16 + lr) * APITCH + kk * 32 + lh * 8];
  }
}

// 32 rows x 64 cols: stream b per col-tile q (only b[8] live), acc[q][rh]
__device__ __forceinline__ void gemm4q(const bf16x8 (&a)[2][8],
                                       const unsigned short* __restrict__ W,
                                       f32x4 (&acc)[4][2], int wv, int lane) {
#pragma unroll
  for (int q = 0; q < 4; q++) {
    const unsigned short* Wp = W + ((wv * 4 + q) << 12) + lane * 8;
    bf16x8 b[8];
#pragma unroll
    for (int kk = 0; kk < 8; kk++) b[kk] = *(const bf16x8*)&Wp[kk * 512];
    acc[q][0] = (f32x4){0.f, 0.f, 0.f, 0.f};
    acc[q][1] = (f32x4){0.f, 0.f, 0.f, 0.f};
#pragma unroll
    for (int kk = 0; kk < 8; kk++) {
      acc[q][0] = __builtin_amdgcn_mfma_f32_16x16x32_bf16(a[0][kk], b[kk], acc[q][0], 0, 0, 0);
      acc[q][1] = __builtin_amdgcn_mfma_f32_16x16x32_bf16(a[1][kk], b[kk], acc[q][1], 0, 0, 0);
    }
  }
}

__device__ __forceinline__ void statsW(const f32x4 (&acc)[4][2], const float (&b4)[4],
                                       float* sP, float* qP, int wv, int lr, int lh) {
#pragma unroll
  for (int rh = 0; rh < 2; rh++)
#pragma unroll
    for (int i = 0; i < 4; i++) {
      float s = 0.f, qq = 0.f;
#pragma unroll
      for (int q = 0; q < 4; q++) { float v = acc[q][rh][i] + b4[q]; s += v; qq += v * v; }
#pragma unroll
      for (int m = 1; m < 16; m <<= 1) { s += __shfl_xor(s, m); qq += __shfl_xor(qq, m); }
      if (lr == 0) {
        int r = rh * 16 + lh * 4 + i;
        sP[wv * 32 + r] = s; qP[wv * 32 + r] = qq;
      }
    }
}
__device__ __forceinline__ void statsR(const float* sP, const float* qP,
                                       float (&mu)[2][4], float (&rs)[2][4], int lh) {
#pragma unroll
  for (int rh = 0; rh < 2; rh++)
#pragma unroll
    for (int i = 0; i < 4; i++) {
      int r = rh * 16 + lh * 4 + i;
      float S = sP[r] + sP[32 + r] + sP[64 + r] + sP[96 + r];
      float Q = qP[r] + qP[32 + r] + qP[64 + r] + qP[96 + r];
      float m = S * (1.f / 256.f);
      mu[rh][i] = m;
      rs[rh][i] = rsqrtf(Q * (1.f / 256.f) - m * m + EPS);
    }
}

// ---------------- main fused kernel: 256 thr, wave = 32 rows x 64 cols ----------------
__global__ __launch_bounds__(256, 3) void k_main(
    const float* __restrict__ inf,
    const unsigned short* __restrict__ inpWf, const float* __restrict__ inpb,
    const unsigned short* __restrict__ igWf, const float* __restrict__ igb,
    const unsigned short* __restrict__ ugWf, const float* __restrict__ ugb,
    const unsigned short* __restrict__ fcWf, const float* __restrict__ fcb,
    const float* __restrict__ nig, const float* __restrict__ nib,
    const float* __restrict__ iig, const float* __restrict__ iib,
    const float* __restrict__ iog, const float* __restrict__ iob,
    const float* __restrict__ fng, const float* __restrict__ fnb,
    const float* __restrict__ param_in, const float* __restrict__ param_out_ln,
    float* __restrict__ out) {
  __shared__ short aT[32 * APITCH];
  __shared__ short gT[32 * APITCH];
  __shared__ float sP[2][128], qP[2][128];

  const int t = threadIdx.x;
  const int wv = t >> 6, lane = t & 63, lr = lane & 15, lh = lane >> 4;
  const int cb = wv * 64;
  const int r0 = blockIdx.x * 32;

  // stage 32x256 f32 -> bf16 LDS (coalesced float4)
#pragma unroll
  for (int j = 0; j < 8; j++) {
    const int idx4 = j * 256 + t;
    const int row = idx4 >> 6;
    const int c4 = (idx4 & 63) << 2;
    const float4 v = *(const float4*)&inf[(size_t)(r0 + row) * 256 + c4];
    short* p = &aT[row * APITCH + c4];
    p[0] = (short)f2b(v.x); p[1] = (short)f2b(v.y);
    p[2] = (short)f2b(v.z); p[3] = (short)f2b(v.w);
  }

  int nrow[2][4];
#pragma unroll
  for (int rh = 0; rh < 2; rh++)
#pragma unroll
    for (int i = 0; i < 4; i++)
      nrow[rh][i] = (int)((unsigned)(r0 + rh * 16 + lh * 4 + i) / 9u);

  __syncthreads();

  bf16x8 a[2][8];
  f32x4 acc[4][2];
  float b4[4], mu[2][4], rs[2][4];
  unsigned gio[4][2][2];   // packed bf16 pairs per (q, rh)

  loadA2(aT, a, lr, lh);

  // ---- PH0: input_in -> gate_feats -> gT ----
  gemm4q(a, inpWf, acc, wv, lane);
#pragma unroll
  for (int q = 0; q < 4; q++) b4[q] = inpb[cb + q * 16 + lr];
#pragma unroll
  for (int q = 0; q < 4; q++) {
    const int col = cb + q * 16 + lr;
#pragma unroll
    for (int rh = 0; rh < 2; rh++)
#pragma unroll
      for (int i = 0; i < 4; i++) {
        float g = (acc[q][rh][i] + b4[q]) * param_in[(size_t)nrow[rh][i] * 256 + col];
        gT[(rh * 16 + lh * 4 + i) * APITCH + col] = (short)f2b(g);
      }
  }

  // ---- PH1: input_out, LN -> gio (ioLN packed) ----
  gemm4q(a, inpWf + (16 << 12), acc, wv, lane);
#pragma unroll
  for (int q = 0; q < 4; q++) b4[q] = inpb[256 + cb + q * 16 + lr];
  statsW(acc, b4, sP[1], qP[1], wv, lr, lh);
  __syncthreads();
  statsR(sP[1], qP[1], mu, rs, lh);
#pragma unroll
  for (int q = 0; q < 4; q++) {
    const int col = cb + q * 16 + lr;
    const float ga = iog[col], be = iob[col];
#pragma unroll
    for (int rh = 0; rh < 2; rh++) {
      float v0 = (acc[q][rh][0] + b4[q] - mu[rh][0]) * rs[rh][0] * ga + be;
      float v1 = (acc[q][rh][1] + b4[q] - mu[rh][1]) * rs[rh][1] * ga + be;
      float v2 = (acc[q][rh][2] + b4[q] - mu[rh][2]) * rs[rh][2] * ga + be;
      float v3 = (acc[q][rh][3] + b4[q] - mu[rh][3]) * rs[rh][3] * ga + be;
      gio[q][rh][0] = (unsigned)f2b(v0) | ((unsigned)f2b(v1) << 16);
      gio[q][rh][1] = (unsigned)f2b(v2) | ((unsigned)f2b(v3) << 16);
    }
  }

  // ---- PH2: ig gate on gate_feats; gio <- g1 * ioLN ----
  loadA2(gT, a, lr, lh);
  gemm4q(a, igWf, acc, wv, lane);
#pragma unroll
  for (int q = 0; q < 4; q++) b4[q] = igb[cb + q * 16 + lr];
  statsW(acc, b4, sP[0], qP[0], wv, lr, lh);
  __syncthreads();
  statsR(sP[0], qP[0], mu, rs, lh);
#pragma unroll
  for (int q = 0; q < 4; q++) {
    const int col = cb + q * 16 + lr;
    const float ga = iig[col], be = iib[col];
#pragma unroll
    for (int rh = 0; rh < 2; rh++) {
      float v[4];
#pragma unroll
      for (int i = 0; i < 4; i++) {
        float p = (acc[q][rh][i] + b4[q] - mu[rh][i]) * rs[rh][i] * ga + be;
        float g1 = 1.f / (1.f + __expf(-p));
        v[i] = g1 * bhalf(gio[q][rh][i >> 1], i & 1);
      }
      gio[q][rh][0] = (unsigned)f2b(v[0]) | ((unsigned)f2b(v[1]) << 16);
      gio[q][rh][1] = (unsigned)f2b(v[2]) | ((unsigned)f2b(v[3]) << 16);
    }
  }

  // ---- PH3: ug gate; features = g2*param_out_ln + gio -> aT ----
  gemm4q(a, ugWf, acc, wv, lane);
#pragma unroll
  for (int q = 0; q < 4; q++) b4[q] = ugb[cb + q * 16 + lr];
  statsW(acc, b4, sP[1], qP[1], wv, lr, lh);
  __syncthreads();
  statsR(sP[1], qP[1], mu, rs, lh);
#pragma unroll
  for (int q = 0; q < 4; q++) {
    const int col = cb + q * 16 + lr;
    const float ga = nig[col], be = nib[col];
#pragma unroll
    for (int rh = 0; rh < 2; rh++)
#pragma unroll
      for (int i = 0; i < 4; i++) {
        float u = (acc[q][rh][i] + b4[q] - mu[rh][i]) * rs[rh][i] * ga + be;
        float g2 = 1.f / (1.f + __expf(-u));
        float po = param_out_ln[(size_t)nrow[rh][i] * 256 + col];
        float ft = g2 * po + bhalf(gio[q][rh][i >> 1], i & 1);
        aT[(rh * 16 + lh * 4 + i) * APITCH + col] = (short)f2b(ft);
      }
  }
  __syncthreads();   // aT(features) ready

  // ---- PH4: fc, LN, relu -> out (direct stores; q-pairs merge to full lines) ----
  loadA2(aT, a, lr, lh);
  gemm4q(a, fcWf, acc, wv, lane);
#pragma unroll
  for (int q = 0; q < 4; q++) b4[q] = fcb[cb + q * 16 + lr];
  statsW(acc, b4, sP[0], qP[0], wv, lr, lh);
  __syncthreads();
  statsR(sP[0], qP[0], mu, rs, lh);
#pragma unroll
  for (int q = 0; q < 4; q++) {
    const int col = cb + q * 16 + lr;
    const float ga = fng[col], be = fnb[col];
#pragma unroll
    for (int rh = 0; rh < 2; rh++)
#pragma unroll
      for (int i = 0; i < 4; i++) {
        float v = (acc[q][rh][i] + b4[q] - mu[rh][i]) * rs[rh][i] * ga + be;
        out[(size_t)(r0 + rh * 16 + lh * 4 + i) * 256 + col] = fmaxf(v, 0.f);
      }
  }
}

// ---------------- kernel 1: params = uf @ dyn_W^T + dyn_b ----------------
#define FPITCH 516

__device__ __forceinline__ void red8(float& s, float& q) {
#pragma unroll
  for (int m = 1; m < 8; m <<= 1) { s += __shfl_xor(s, m); q += __shfl_xor(q, m); }
}

__global__ __launch_bounds__(256) void k_params(
    const float* __restrict__ uf, const unsigned short* __restrict__ dynWf,
    const float* __restrict__ dynb, const float* __restrict__ nog,
    const float* __restrict__ nob, float* __restrict__ param_in,
    float* __restrict__ param_out_ln) {
  __shared__ short aT[32 * APITCH];
  __shared__ float fBuf[32 * FPITCH];
  const int t = threadIdx.x;
  const int wv = t >> 6, lane = t & 63, lr = lane & 15, lh = lane >> 4;
  const int r0 = blockIdx.x * 32;
#pragma unroll
  for (int j = 0; j < 8; j++) {
    const int idx4 = j * 256 + t;
    const int row = idx4 >> 6;
    const int c4 = (idx4 & 63) << 2;
    const float4 v = *(const float4*)&uf[(size_t)(r0 + row) * 256 + c4];
    short* p = &aT[row * APITCH + c4];
    p[0] = (short)f2b(v.x); p[1] = (short)f2b(v.y);
    p[2] = (short)f2b(v.z); p[3] = (short)f2b(v.w);
  }
  __syncthreads();
  bf16x8 a0[8], a1[8];
#pragma unroll
  for (int kk = 0; kk < 8; kk++) {
    a0[kk] = *(const bf16x8*)&aT[lr * APITCH + kk * 32 + lh * 8];
    a1[kk] = *(const bf16x8*)&aT[(16 + lr) * APITCH + kk * 32 + lh * 8];
  }
#pragma unroll 1
  for (int cp = 0; cp < 8; cp++) {
    const int ct = wv * 8 + cp;
    bf16x8 b[8];
#pragma unroll
    for (int kk = 0; kk < 8; kk++)
      b[kk] = *(const bf16x8*)&dynWf[((ct * 8 + kk) * 64 + lane) * 8];
    const float bi = dynb[ct * 16 + lr];
    f32x4 c0 = {0.f, 0.f, 0.f, 0.f}, c1 = c0;
#pragma unroll
    for (int kk = 0; kk < 8; kk++) {
      c0 = __builtin_amdgcn_mfma_f32_16x16x32_bf16(a0[kk], b[kk], c0, 0, 0, 0);
      c1 = __builtin_amdgcn_mfma_f32_16x16x32_bf16(a1[kk], b[kk], c1, 0, 0, 0);
    }
#pragma unroll
    for (int i = 0; i < 4; i++) {
      fBuf[(lh * 4 + i) * FPITCH + ct * 16 + lr] = c0[i] + bi;
      fBuf[(16 + lh * 4 + i) * FPITCH + ct * 16 + lr] = c1[i] + bi;
    }
  }
  __syncthreads();
  const int row = t >> 3, j = t & 7;
  float s = 0.f, q = 0.f;
#pragma unroll
  for (int i = 0; i < 32; i++) {
    float x = fBuf[row * FPITCH + 256 + j + 8 * i];
    s += x; q += x * x;
  }
  red8(s, q);
  const float mu = s * (1.f / 256.f);
  const float rsv = rsqrtf(q * (1.f / 256.f) - mu * mu + EPS);
#pragma unroll 1
  for (int i = 0; i < 32; i++) {
    const int c = j + 8 * i;
    float x = fBuf[row * FPITCH + 256 + c];
    param_out_ln[(size_t)(r0 + row) * 256 + c] = (x - mu) * rsv * nog[c] + nob[c];
  }
#pragma unroll
  for (int jj = 0; jj < 8; jj++) {
    const int idx4 = jj * 256 + t;
    const int rwq = idx4 >> 6;
    const int c4 = (idx4 & 63) << 2;
    float4 v;
    v.x = fBuf[rwq * FPITCH + c4 + 0];
    v.y = fBuf[rwq * FPITCH + c4 + 1];
    v.z = fBuf[rwq * FPITCH + c4 + 2];
    v.w = fBuf[rwq * FPITCH + c4 + 3];
    *(float4*)&param_in[(size_t)(r0 + rwq) * 256 + c4] = v;
  }
}

extern "C" void kernel_launch(void* const* d_in, const int* in_sizes, int n_in,
                              void* d_out, int out_size, void* d_ws, size_t ws_size,
                              hipStream_t stream) {
  const float* uf   = (const float*)d_in[0];
  const float* inf  = (const float*)d_in[1];
  const float* dynW = (const float*)d_in[2];
  const float* dynb = (const float*)d_in[3];
  const float* inpW = (const float*)d_in[4];
  const float* inpb = (const float*)d_in[5];
  const float* igW  = (const float*)d_in[6];
  const float* igb  = (const float*)d_in[7];
  const float* ugW  = (const float*)d_in[8];
  const float* ugb  = (const float*)d_in[9];
  const float* fcW  = (const float*)d_in[10];
  const float* fcb  = (const float*)d_in[11];
  const float* nig  = (const float*)d_in[12];
  const float* nib  = (const float*)d_in[13];
  const float* nog  = (const float*)d_in[14];
  const float* nob  = (const float*)d_in[15];
  const float* iig  = (const float*)d_in[16];
  const float* iib  = (const float*)d_in[17];
  const float* iog  = (const float*)d_in[18];
  const float* iob  = (const float*)d_in[19];
  const float* fng  = (const float*)d_in[20];
  const float* fnb  = (const float*)d_in[21];
  float* out = (float*)d_out;

  char* ws = (char*)d_ws;
  unsigned short* dynWf = (unsigned short*)(ws + 0);        // 262144 B
  unsigned short* inpWf = (unsigned short*)(ws + 262144);   // 262144 B
  unsigned short* igWf  = (unsigned short*)(ws + 524288);   // 131072 B
  unsigned short* ugWf  = (unsigned short*)(ws + 655360);   // 131072 B
  unsigned short* fcWf  = (unsigned short*)(ws + 786432);   // 131072 B
  float* param_in     = (float*)(ws + (1 << 20));
  float* param_out_ln = (float*)(ws + (1 << 20) + (16 << 20));

  k_cvt_frag<<<dim3(512), dim3(256), 0, stream>>>(dynW, dynWf, 131072);
  k_cvt_frag<<<dim3(512), dim3(256), 0, stream>>>(inpW, inpWf, 131072);
  k_cvt_frag<<<dim3(256), dim3(256), 0, stream>>>(igW, igWf, 65536);
  k_cvt_frag<<<dim3(256), dim3(256), 0, stream>>>(ugW, ugWf, 65536);
  k_cvt_frag<<<dim3(256), dim3(256), 0, stream>>>(fcW, fcWf, 65536);

  k_params<<<dim3(512), dim3(256), 0, stream>>>(uf, dynWf, dynb, nog, nob,
                                                param_in, param_out_ln);

  k_main<<<dim3(4608), dim3(256), 0, stream>>>(
      inf, inpWf, inpb, igWf, igb, ugWf, ugb, fcWf, fcb,
      nig, nib, iig, iib, iog, iob, fng, fnb,
      param_in, param_out_ln, out);
}

// Round 5
// 417.618 us; speedup vs baseline: 1.3811x; 1.2010x over previous
//
#include <hip/hip_runtime.h>

#define EPS 1e-5f
#define APITCH 264   // bf16 tile row pitch (shorts)

typedef __attribute__((ext_vector_type(8))) short bf16x8;
typedef __attribute__((ext_vector_type(4))) float f32x4;

__device__ __forceinline__ unsigned short f2b(float f) {
  unsigned u = __builtin_bit_cast(unsigned, f);
  u += 0x7fffu + ((u >> 16) & 1u);   // RTNE
  return (unsigned short)(u >> 16);
}
__device__ __forceinline__ float bhalf(unsigned pk, int hi) {
  unsigned u = hi ? (pk & 0xffff0000u) : (pk << 16);
  return __builtin_bit_cast(float, u);
}

// Repack W (nrows x 256 f32) into MFMA-fragment-linear bf16:
// dst[(((ct*8+kk)*64+lane)*8)+j] = W[ct*16+(lane&15)][kk*32+(lane>>4)*8+j]
__global__ void k_cvt_frag(const float* __restrict__ src,
                           unsigned short* __restrict__ dst, int n) {
  int i = blockIdx.x * blockDim.x + threadIdx.x;
  if (i >= n) return;
  int j = i & 7, lane = (i >> 3) & 63, kk = (i >> 9) & 7, ct = i >> 12;
  int row = ct * 16 + (lane & 15);
  int col = kk * 32 + (lane >> 4) * 8 + j;
  dst[i] = f2b(src[row * 256 + col]);
}

// load both 16-row halves of a 32x256 bf16 tile into a-frags (16 ds_read_b128)
__device__ __forceinline__ void loadA2(const short* src, bf16x8 (&a)[2][8],
                                       int lr, int lh) {
#pragma unroll
  for (int kk = 0; kk < 8; kk++) {
    a[0][kk] = *(const bf16x8*)&src[lr * APITCH + kk * 32 + lh * 8];
    a[1][kk] = *(const bf16x8*)&src[(16 + lr) * APITCH + kk * 32 + lh * 8];
  }
}

// 32 rows x 64 cols: stream b per col-tile q (only b[8] live), acc[q][rh]
__device__ __forceinline__ void gemm4q(const bf16x8 (&a)[2][8],
                                       const unsigned short* __restrict__ W,
                                       f32x4 (&acc)[4][2], int wv, int lane) {
#pragma unroll
  for (int q = 0; q < 4; q++) {
    const unsigned short* Wp = W + ((wv * 4 + q) << 12) + lane * 8;
    bf16x8 b[8];
#pragma unroll
    for (int kk = 0; kk < 8; kk++) b[kk] = *(const bf16x8*)&Wp[kk * 512];
    acc[q][0] = (f32x4){0.f, 0.f, 0.f, 0.f};
    acc[q][1] = (f32x4){0.f, 0.f, 0.f, 0.f};
#pragma unroll
    for (int kk = 0; kk < 8; kk++) {
      acc[q][0] = __builtin_amdgcn_mfma_f32_16x16x32_bf16(a[0][kk], b[kk], acc[q][0], 0, 0, 0);
      acc[q][1] = __builtin_amdgcn_mfma_f32_16x16x32_bf16(a[1][kk], b[kk], acc[q][1], 0, 0, 0);
    }
  }
}

__device__ __forceinline__ void statsW(const f32x4 (&acc)[4][2], const float (&b4)[4],
                                       float* sP, float* qP, int wv, int lr, int lh) {
#pragma unroll
  for (int rh = 0; rh < 2; rh++)
#pragma unroll
    for (int i = 0; i < 4; i++) {
      float s = 0.f, qq = 0.f;
#pragma unroll
      for (int q = 0; q < 4; q++) { float v = acc[q][rh][i] + b4[q]; s += v; qq += v * v; }
#pragma unroll
      for (int m = 1; m < 16; m <<= 1) { s += __shfl_xor(s, m); qq += __shfl_xor(qq, m); }
      if (lr == 0) {
        int r = rh * 16 + lh * 4 + i;
        sP[wv * 32 + r] = s; qP[wv * 32 + r] = qq;
      }
    }
}
__device__ __forceinline__ void statsR(const float* sP, const float* qP,
                                       float (&mu)[2][4], float (&rs)[2][4], int lh) {
#pragma unroll
  for (int rh = 0; rh < 2; rh++)
#pragma unroll
    for (int i = 0; i < 4; i++) {
      int r = rh * 16 + lh * 4 + i;
      float S = sP[r] + sP[32 + r] + sP[64 + r] + sP[96 + r];
      float Q = qP[r] + qP[32 + r] + qP[64 + r] + qP[96 + r];
      float m = S * (1.f / 256.f);
      mu[rh][i] = m;
      rs[rh][i] = rsqrtf(Q * (1.f / 256.f) - m * m + EPS);
    }
}

// ---------------- main fused kernel: 256 thr, wave = 32 rows x 64 cols ----------------
// NOTE: no min-waves arg — a second __launch_bounds__ argument halves the usable
// arch-VGPR budget on MFMA kernels (observed cap = 256/minwaves) and forces scratch.
__global__ __launch_bounds__(256) void k_main(
    const float* __restrict__ inf,
    const unsigned short* __restrict__ inpWf, const float* __restrict__ inpb,
    const unsigned short* __restrict__ igWf, const float* __restrict__ igb,
    const unsigned short* __restrict__ ugWf, const float* __restrict__ ugb,
    const unsigned short* __restrict__ fcWf, const float* __restrict__ fcb,
    const float* __restrict__ nig, const float* __restrict__ nib,
    const float* __restrict__ iig, const float* __restrict__ iib,
    const float* __restrict__ iog, const float* __restrict__ iob,
    const float* __restrict__ fng, const float* __restrict__ fnb,
    const float* __restrict__ param_in, const float* __restrict__ param_out_ln,
    float* __restrict__ out) {
  __shared__ short aT[32 * APITCH];
  __shared__ short gT[32 * APITCH];
  __shared__ float sP[2][128], qP[2][128];

  const int t = threadIdx.x;
  const int wv = t >> 6, lane = t & 63, lr = lane & 15, lh = lane >> 4;
  const int cb = wv * 64;
  const int r0 = blockIdx.x * 32;

  // stage 32x256 f32 -> bf16 LDS (coalesced float4)
#pragma unroll
  for (int j = 0; j < 8; j++) {
    const int idx4 = j * 256 + t;
    const int row = idx4 >> 6;
    const int c4 = (idx4 & 63) << 2;
    const float4 v = *(const float4*)&inf[(size_t)(r0 + row) * 256 + c4];
    short* p = &aT[row * APITCH + c4];
    p[0] = (short)f2b(v.x); p[1] = (short)f2b(v.y);
    p[2] = (short)f2b(v.z); p[3] = (short)f2b(v.w);
  }

  int nrow[2][4];
#pragma unroll
  for (int rh = 0; rh < 2; rh++)
#pragma unroll
    for (int i = 0; i < 4; i++)
      nrow[rh][i] = (int)((unsigned)(r0 + rh * 16 + lh * 4 + i) / 9u);

  __syncthreads();

  bf16x8 a[2][8];
  f32x4 acc[4][2];
  float b4[4], mu[2][4], rs[2][4];
  unsigned gio[4][2][2];   // packed bf16 pairs per (q, rh)

  loadA2(aT, a, lr, lh);

  // ---- PH0: input_in -> gate_feats -> gT ----
  gemm4q(a, inpWf, acc, wv, lane);
#pragma unroll
  for (int q = 0; q < 4; q++) b4[q] = inpb[cb + q * 16 + lr];
#pragma unroll
  for (int q = 0; q < 4; q++) {
    const int col = cb + q * 16 + lr;
#pragma unroll
    for (int rh = 0; rh < 2; rh++)
#pragma unroll
      for (int i = 0; i < 4; i++) {
        float g = (acc[q][rh][i] + b4[q]) * param_in[(size_t)nrow[rh][i] * 256 + col];
        gT[(rh * 16 + lh * 4 + i) * APITCH + col] = (short)f2b(g);
      }
  }

  // ---- PH1: input_out, LN -> gio (ioLN packed) ----
  gemm4q(a, inpWf + (16 << 12), acc, wv, lane);
#pragma unroll
  for (int q = 0; q < 4; q++) b4[q] = inpb[256 + cb + q * 16 + lr];
  statsW(acc, b4, sP[1], qP[1], wv, lr, lh);
  __syncthreads();
  statsR(sP[1], qP[1], mu, rs, lh);
#pragma unroll
  for (int q = 0; q < 4; q++) {
    const int col = cb + q * 16 + lr;
    const float ga = iog[col], be = iob[col];
#pragma unroll
    for (int rh = 0; rh < 2; rh++) {
      float v0 = (acc[q][rh][0] + b4[q] - mu[rh][0]) * rs[rh][0] * ga + be;
      float v1 = (acc[q][rh][1] + b4[q] - mu[rh][1]) * rs[rh][1] * ga + be;
      float v2 = (acc[q][rh][2] + b4[q] - mu[rh][2]) * rs[rh][2] * ga + be;
      float v3 = (acc[q][rh][3] + b4[q] - mu[rh][3]) * rs[rh][3] * ga + be;
      gio[q][rh][0] = (unsigned)f2b(v0) | ((unsigned)f2b(v1) << 16);
      gio[q][rh][1] = (unsigned)f2b(v2) | ((unsigned)f2b(v3) << 16);
    }
  }

  // ---- PH2: ig gate on gate_feats; gio <- g1 * ioLN ----
  loadA2(gT, a, lr, lh);
  gemm4q(a, igWf, acc, wv, lane);
#pragma unroll
  for (int q = 0; q < 4; q++) b4[q] = igb[cb + q * 16 + lr];
  statsW(acc, b4, sP[0], qP[0], wv, lr, lh);
  __syncthreads();
  statsR(sP[0], qP[0], mu, rs, lh);
#pragma unroll
  for (int q = 0; q < 4; q++) {
    const int col = cb + q * 16 + lr;
    const float ga = iig[col], be = iib[col];
#pragma unroll
    for (int rh = 0; rh < 2; rh++) {
      float v[4];
#pragma unroll
      for (int i = 0; i < 4; i++) {
        float p = (acc[q][rh][i] + b4[q] - mu[rh][i]) * rs[rh][i] * ga + be;
        float g1 = 1.f / (1.f + __expf(-p));
        v[i] = g1 * bhalf(gio[q][rh][i >> 1], i & 1);
      }
      gio[q][rh][0] = (unsigned)f2b(v[0]) | ((unsigned)f2b(v[1]) << 16);
      gio[q][rh][1] = (unsigned)f2b(v[2]) | ((unsigned)f2b(v[3]) << 16);
    }
  }

  // ---- PH3: ug gate; features = g2*param_out_ln + gio -> aT ----
  gemm4q(a, ugWf, acc, wv, lane);
#pragma unroll
  for (int q = 0; q < 4; q++) b4[q] = ugb[cb + q * 16 + lr];
  statsW(acc, b4, sP[1], qP[1], wv, lr, lh);
  __syncthreads();
  statsR(sP[1], qP[1], mu, rs, lh);
#pragma unroll
  for (int q = 0; q < 4; q++) {
    const int col = cb + q * 16 + lr;
    const float ga = nig[col], be = nib[col];
#pragma unroll
    for (int rh = 0; rh < 2; rh++)
#pragma unroll
      for (int i = 0; i < 4; i++) {
        float u = (acc[q][rh][i] + b4[q] - mu[rh][i]) * rs[rh][i] * ga + be;
        float g2 = 1.f / (1.f + __expf(-u));
        float po = param_out_ln[(size_t)nrow[rh][i] * 256 + col];
        float ft = g2 * po + bhalf(gio[q][rh][i >> 1], i & 1);
        aT[(rh * 16 + lh * 4 + i) * APITCH + col] = (short)f2b(ft);
      }
  }
  __syncthreads();   // aT(features) ready

  // ---- PH4: fc, LN, relu -> out (direct stores; q-pairs merge to full lines) ----
  loadA2(aT, a, lr, lh);
  gemm4q(a, fcWf, acc, wv, lane);
#pragma unroll
  for (int q = 0; q < 4; q++) b4[q] = fcb[cb + q * 16 + lr];
  statsW(acc, b4, sP[0], qP[0], wv, lr, lh);
  __syncthreads();
  statsR(sP[0], qP[0], mu, rs, lh);
#pragma unroll
  for (int q = 0; q < 4; q++) {
    const int col = cb + q * 16 + lr;
    const float ga = fng[col], be = fnb[col];
#pragma unroll
    for (int rh = 0; rh < 2; rh++)
#pragma unroll
      for (int i = 0; i < 4; i++) {
        float v = (acc[q][rh][i] + b4[q] - mu[rh][i]) * rs[rh][i] * ga + be;
        out[(size_t)(r0 + rh * 16 + lh * 4 + i) * 256 + col] = fmaxf(v, 0.f);
      }
  }
}

// ---------------- kernel 1: params = uf @ dyn_W^T + dyn_b ----------------
#define FPITCH 516

__device__ __forceinline__ void red8(float& s, float& q) {
#pragma unroll
  for (int m = 1; m < 8; m <<= 1) { s += __shfl_xor(s, m); q += __shfl_xor(q, m); }
}

__global__ __launch_bounds__(256) void k_params(
    const float* __restrict__ uf, const unsigned short* __restrict__ dynWf,
    const float* __restrict__ dynb, const float* __restrict__ nog,
    const float* __restrict__ nob, float* __restrict__ param_in,
    float* __restrict__ param_out_ln) {
  __shared__ short aT[32 * APITCH];
  __shared__ float fBuf[32 * FPITCH];
  const int t = threadIdx.x;
  const int wv = t >> 6, lane = t & 63, lr = lane & 15, lh = lane >> 4;
  const int r0 = blockIdx.x * 32;
#pragma unroll
  for (int j = 0; j < 8; j++) {
    const int idx4 = j * 256 + t;
    const int row = idx4 >> 6;
    const int c4 = (idx4 & 63) << 2;
    const float4 v = *(const float4*)&uf[(size_t)(r0 + row) * 256 + c4];
    short* p = &aT[row * APITCH + c4];
    p[0] = (short)f2b(v.x); p[1] = (short)f2b(v.y);
    p[2] = (short)f2b(v.z); p[3] = (short)f2b(v.w);
  }
  __syncthreads();
  bf16x8 a0[8], a1[8];
#pragma unroll
  for (int kk = 0; kk < 8; kk++) {
    a0[kk] = *(const bf16x8*)&aT[lr * APITCH + kk * 32 + lh * 8];
    a1[kk] = *(const bf16x8*)&aT[(16 + lr) * APITCH + kk * 32 + lh * 8];
  }
#pragma unroll 1
  for (int cp = 0; cp < 8; cp++) {
    const int ct = wv * 8 + cp;
    bf16x8 b[8];
#pragma unroll
    for (int kk = 0; kk < 8; kk++)
      b[kk] = *(const bf16x8*)&dynWf[((ct * 8 + kk) * 64 + lane) * 8];
    const float bi = dynb[ct * 16 + lr];
    f32x4 c0 = {0.f, 0.f, 0.f, 0.f}, c1 = c0;
#pragma unroll
    for (int kk = 0; kk < 8; kk++) {
      c0 = __builtin_amdgcn_mfma_f32_16x16x32_bf16(a0[kk], b[kk], c0, 0, 0, 0);
      c1 = __builtin_amdgcn_mfma_f32_16x16x32_bf16(a1[kk], b[kk], c1, 0, 0, 0);
    }
#pragma unroll
    for (int i = 0; i < 4; i++) {
      fBuf[(lh * 4 + i) * FPITCH + ct * 16 + lr] = c0[i] + bi;
      fBuf[(16 + lh * 4 + i) * FPITCH + ct * 16 + lr] = c1[i] + bi;
    }
  }
  __syncthreads();
  const int row = t >> 3, j = t & 7;
  float s = 0.f, q = 0.f;
#pragma unroll
  for (int i = 0; i < 32; i++) {
    float x = fBuf[row * FPITCH + 256 + j + 8 * i];
    s += x; q += x * x;
  }
  red8(s, q);
  const float mu = s * (1.f / 256.f);
  const float rsv = rsqrtf(q * (1.f / 256.f) - mu * mu + EPS);
#pragma unroll 1
  for (int i = 0; i < 32; i++) {
    const int c = j + 8 * i;
    float x = fBuf[row * FPITCH + 256 + c];
    param_out_ln[(size_t)(r0 + row) * 256 + c] = (x - mu) * rsv * nog[c] + nob[c];
  }
#pragma unroll
  for (int jj = 0; jj < 8; jj++) {
    const int idx4 = jj * 256 + t;
    const int rwq = idx4 >> 6;
    const int c4 = (idx4 & 63) << 2;
    float4 v;
    v.x = fBuf[rwq * FPITCH + c4 + 0];
    v.y = fBuf[rwq * FPITCH + c4 + 1];
    v.z = fBuf[rwq * FPITCH + c4 + 2];
    v.w = fBuf[rwq * FPITCH + c4 + 3];
    *(float4*)&param_in[(size_t)(r0 + rwq) * 256 + c4] = v;
  }
}

extern "C" void kernel_launch(void* const* d_in, const int* in_sizes, int n_in,
                              void* d_out, int out_size, void* d_ws, size_t ws_size,
                              hipStream_t stream) {
  const float* uf   = (const float*)d_in[0];
  const float* inf  = (const float*)d_in[1];
  const float* dynW = (const float*)d_in[2];
  const float* dynb = (const float*)d_in[3];
  const float* inpW = (const float*)d_in[4];
  const float* inpb = (const float*)d_in[5];
  const float* igW  = (const float*)d_in[6];
  const float* igb  = (const float*)d_in[7];
  const float* ugW  = (const float*)d_in[8];
  const float* ugb  = (const float*)d_in[9];
  const float* fcW  = (const float*)d_in[10];
  const float* fcb  = (const float*)d_in[11];
  const float* nig  = (const float*)d_in[12];
  const float* nib  = (const float*)d_in[13];
  const float* nog  = (const float*)d_in[14];
  const float* nob  = (const float*)d_in[15];
  const float* iig  = (const float*)d_in[16];
  const float* iib  = (const float*)d_in[17];
  const float* iog  = (const float*)d_in[18];
  const float* iob  = (const float*)d_in[19];
  const float* fng  = (const float*)d_in[20];
  const float* fnb  = (const float*)d_in[21];
  float* out = (float*)d_out;

  char* ws = (char*)d_ws;
  unsigned short* dynWf = (unsigned short*)(ws + 0);        // 262144 B
  unsigned short* inpWf = (unsigned short*)(ws + 262144);   // 262144 B
  unsigned short* igWf  = (unsigned short*)(ws + 524288);   // 131072 B
  unsigned short* ugWf  = (unsigned short*)(ws + 655360);   // 131072 B
  unsigned short* fcWf  = (unsigned short*)(ws + 786432);   // 131072 B
  float* param_in     = (float*)(ws + (1 << 20));
  float* param_out_ln = (float*)(ws + (1 << 20) + (16 << 20));

  k_cvt_frag<<<dim3(512), dim3(256), 0, stream>>>(dynW, dynWf, 131072);
  k_cvt_frag<<<dim3(512), dim3(256), 0, stream>>>(inpW, inpWf, 131072);
  k_cvt_frag<<<dim3(256), dim3(256), 0, stream>>>(igW, igWf, 65536);
  k_cvt_frag<<<dim3(256), dim3(256), 0, stream>>>(ugW, ugWf, 65536);
  k_cvt_frag<<<dim3(256), dim3(256), 0, stream>>>(fcW, fcWf, 65536);

  k_params<<<dim3(512), dim3(256), 0, stream>>>(uf, dynWf, dynb, nog, nob,
                                                param_in, param_out_ln);

  k_main<<<dim3(4608), dim3(256), 0, stream>>>(
      inf, inpWf, inpb, igWf, igb, ugWf, ugb, fcWf, fcb,
      nig, nib, iig, iib, iog, iob, fng, fnb,
      param_in, param_out_ln, out);
}